// Round 1
// baseline (1780.850 us; speedup 1.0000x reference)
//
#include <hip/hip_runtime.h>

// Problem constants (match reference)
constexpr int NN = 100000;   // nodes
constexpr int EE = 3200000;  // edges
constexpr int BLOCK = 256;
constexpr int SCAN_CHUNK = 1024;
constexpr int SCAN_B = (NN + SCAN_CHUNK - 1) / SCAN_CHUNK;  // 98 blocks

// ---------------- degree / dinv ----------------
__global__ __launch_bounds__(BLOCK) void k_degree(const int* __restrict__ dst,
                                                  int* __restrict__ deg) {
  int e = blockIdx.x * BLOCK + threadIdx.x;
  if (e < EE) atomicAdd(&deg[dst[e]], 1);
}

__global__ __launch_bounds__(BLOCK) void k_dinv(const int* __restrict__ deg,
                                                float* __restrict__ dinv) {
  int i = blockIdx.x * BLOCK + threadIdx.x;
  if (i < NN) dinv[i] = rsqrtf((float)(deg[i] + 1));  // +1 self loop
}

// ---------------- exclusive prefix sum over deg[NN] -> rowptr[NN+1] ----------------
__global__ __launch_bounds__(BLOCK) void k_scan1(const int* __restrict__ v,
                                                 int* __restrict__ bsum) {
  __shared__ int s[BLOCK];
  int base = blockIdx.x * SCAN_CHUNK;
  int t = threadIdx.x;
  int sum = 0;
#pragma unroll
  for (int j = 0; j < 4; ++j) {
    int i = base + t * 4 + j;
    if (i < NN) sum += v[i];
  }
  s[t] = sum;
  __syncthreads();
  for (int off = 128; off > 0; off >>= 1) {
    if (t < off) s[t] += s[t + off];
    __syncthreads();
  }
  if (t == 0) bsum[blockIdx.x] = s[0];
}

__global__ __launch_bounds__(BLOCK) void k_scan2(int* __restrict__ bsum) {
  __shared__ int s[BLOCK];
  int t = threadIdx.x;
  int v = (t < SCAN_B) ? bsum[t] : 0;
  s[t] = v;
  __syncthreads();
  for (int off = 1; off < BLOCK; off <<= 1) {
    int x = (t >= off) ? s[t - off] : 0;
    __syncthreads();
    s[t] += x;
    __syncthreads();
  }
  if (t < SCAN_B) bsum[t] = s[t] - v;        // exclusive
  if (t == BLOCK - 1) bsum[SCAN_B] = s[t];   // total (== EE)
}

__global__ __launch_bounds__(BLOCK) void k_scan3(const int* __restrict__ v,
                                                 const int* __restrict__ bsum,
                                                 int* __restrict__ rowptr) {
  __shared__ int s[BLOCK];
  int base = blockIdx.x * SCAN_CHUNK;
  int t = threadIdx.x;
  int loc[4];
  int sum = 0;
#pragma unroll
  for (int j = 0; j < 4; ++j) {
    int i = base + t * 4 + j;
    loc[j] = (i < NN) ? v[i] : 0;
    sum += loc[j];
  }
  s[t] = sum;
  __syncthreads();
  int own = sum;
  for (int off = 1; off < BLOCK; off <<= 1) {
    int x = (t >= off) ? s[t - off] : 0;
    __syncthreads();
    s[t] += x;
    __syncthreads();
  }
  int ex = s[t] - own + bsum[blockIdx.x];
#pragma unroll
  for (int j = 0; j < 4; ++j) {
    int i = base + t * 4 + j;
    if (i < NN) {
      rowptr[i] = ex;
      ex += loc[j];
    }
  }
  if (blockIdx.x == 0 && t == 0) rowptr[NN] = bsum[SCAN_B];
}

// ---------------- CSR fill ----------------
__global__ __launch_bounds__(BLOCK) void k_fill(const int* __restrict__ src,
                                                const int* __restrict__ dst,
                                                const int* __restrict__ rowptr,
                                                int* __restrict__ fill,
                                                int* __restrict__ col) {
  int e = blockIdx.x * BLOCK + threadIdx.x;
  if (e >= EE) return;
  int d = dst[e];
  int pos = atomicAdd(&fill[d], 1);
  col[rowptr[d] + pos] = src[e];
}

// ---------------- dense transform: out = act(h @ W [+ b]) [* dinv] ----------------
template <int FIN, int FOUT, bool BIAS, bool RELU, bool SCALE>
__global__ __launch_bounds__(BLOCK) void k_gemm(const float* __restrict__ h,
                                                float* __restrict__ out,
                                                const float* __restrict__ W,
                                                const float* __restrict__ b,
                                                const float* __restrict__ dinv) {
  constexpr int NPB = BLOCK / FOUT;  // nodes per block
  __shared__ float Ws[FIN * FOUT];
  __shared__ float Hs[NPB][FIN];
  int tid = threadIdx.x;
  for (int i = tid; i < FIN * FOUT; i += BLOCK) Ws[i] = W[i];
  int node0 = blockIdx.x * NPB;
  for (int i = tid; i < NPB * FIN; i += BLOCK) {
    int n = i / FIN, k = i % FIN;
    int node = node0 + n;
    Hs[n][k] = (node < NN) ? h[node * FIN + k] : 0.f;
  }
  __syncthreads();
  int n = tid / FOUT, f = tid % FOUT;
  int node = node0 + n;
  if (node >= NN) return;
  float acc = 0.f;
#pragma unroll
  for (int k = 0; k < FIN; ++k) acc = fmaf(Hs[n][k], Ws[k * FOUT + f], acc);
  if (BIAS) acc += b[f];
  if (RELU) acc = fmaxf(acc, 0.f);
  if (SCALE) acc *= dinv[node];
  out[node * FOUT + f] = acc;
}

// ---------------- row scale: t = h * dinv (F=32) ----------------
__global__ __launch_bounds__(BLOCK) void k_scale32(const float* __restrict__ h,
                                                   float* __restrict__ out,
                                                   const float* __restrict__ dinv) {
  int idx = blockIdx.x * BLOCK + threadIdx.x;
  if (idx < NN * 32) out[idx] = h[idx] * dinv[idx >> 5];
}

// ---------------- aggregation: out[i] = dinv[i]*(t[i] + sum_{src->i} t[src]) ----------------
// MODE 0: plain   MODE 1: +bias, relu
template <int F, int MODE>
__global__ __launch_bounds__(BLOCK) void k_agg(const float* __restrict__ t,
                                               float* __restrict__ out,
                                               const int* __restrict__ rowptr,
                                               const int* __restrict__ col,
                                               const float* __restrict__ dinv,
                                               const float* __restrict__ bias) {
  constexpr int NPB = BLOCK / F;
  int node = blockIdx.x * NPB + threadIdx.x / F;
  int f = threadIdx.x % F;
  if (node >= NN) return;
  float acc = t[node * F + f];  // self loop (t already scaled by dinv[node])
  int beg = rowptr[node], end = rowptr[node + 1];
#pragma unroll 4
  for (int e = beg; e < end; ++e) {
    int s = col[e];
    acc += t[s * F + f];
  }
  float v = dinv[node] * acc;
  if (MODE == 1) v = fmaxf(v + bias[f], 0.f);
  out[node * F + f] = v;
}

// ---------------- final: out[i] = h[i,:] . w + b ----------------
__global__ __launch_bounds__(BLOCK) void k_fc2(const float* __restrict__ h,
                                               float* __restrict__ out,
                                               const float* __restrict__ w,
                                               const float* __restrict__ b) {
  __shared__ float ws[32];
  if (threadIdx.x < 32) ws[threadIdx.x] = w[threadIdx.x];
  __syncthreads();
  int i = blockIdx.x * BLOCK + threadIdx.x;
  if (i >= NN) return;
  float acc = b[0];
#pragma unroll
  for (int k = 0; k < 32; ++k) acc = fmaf(h[i * 32 + k], ws[k], acc);
  out[i] = acc;
}

extern "C" void kernel_launch(void* const* d_in, const int* in_sizes, int n_in,
                              void* d_out, int out_size, void* d_ws, size_t ws_size,
                              hipStream_t stream) {
  const float* x = (const float*)d_in[0];
  const int* ei = (const int*)d_in[1];
  const int* esrc = ei;
  const int* edst = ei + EE;
  const float* fc1_w = (const float*)d_in[2];
  const float* fc1_b = (const float*)d_in[3];
  const float* w1 = (const float*)d_in[4];
  const float* b1 = (const float*)d_in[5];
  const float* w2 = (const float*)d_in[6];
  const float* b2 = (const float*)d_in[7];
  const float* w3 = (const float*)d_in[8];
  const float* b3 = (const float*)d_in[9];
  const float* fc2_w = (const float*)d_in[10];
  const float* fc2_b = (const float*)d_in[11];

  // workspace carve (256B aligned)
  char* p = (char*)d_ws;
  auto carve = [&](size_t bytes) {
    void* r = (void*)p;
    p += (bytes + 255) & ~(size_t)255;
    return r;
  };
  float* dinv = (float*)carve(NN * sizeof(float));
  int* deg = (int*)carve(NN * sizeof(int));
  int* rowptr = (int*)carve((NN + 1) * sizeof(int));
  int* fillp = (int*)carve(NN * sizeof(int));
  int* bsum = (int*)carve((SCAN_B + 1) * sizeof(int));
  int* col = (int*)carve(EE * sizeof(int));
  float* bufA = (float*)carve((size_t)NN * 64 * sizeof(float));
  float* bufB = (float*)carve((size_t)NN * 64 * sizeof(float));

  hipMemsetAsync(deg, 0, NN * sizeof(int), stream);
  hipMemsetAsync(fillp, 0, NN * sizeof(int), stream);

  k_degree<<<EE / BLOCK, BLOCK, 0, stream>>>(edst, deg);
  k_dinv<<<(NN + BLOCK - 1) / BLOCK, BLOCK, 0, stream>>>(deg, dinv);
  k_scan1<<<SCAN_B, BLOCK, 0, stream>>>(deg, bsum);
  k_scan2<<<1, BLOCK, 0, stream>>>(bsum);
  k_scan3<<<SCAN_B, BLOCK, 0, stream>>>(deg, bsum, rowptr);
  k_fill<<<EE / BLOCK, BLOCK, 0, stream>>>(esrc, edst, rowptr, fillp, col);

  // h0 = x @ fc1_w + fc1_b   (N x 3 -> N x 32), bias, no relu
  k_gemm<3, 32, true, false, false>
      <<<(NN + 7) / 8, BLOCK, 0, stream>>>(x, bufA, fc1_w, fc1_b, nullptr);

  float* h = bufA;
  float* t = bufB;
  auto swap = [&]() { float* tmp = h; h = t; t = tmp; };

  for (int it = 0; it < 4; ++it) {
    // L1 (32->64): aggregate-first (cheaper at F=32)
    k_scale32<<<(NN * 32) / BLOCK, BLOCK, 0, stream>>>(h, t, dinv);
    swap();
    k_agg<32, 0><<<(NN + 7) / 8, BLOCK, 0, stream>>>(h, t, rowptr, col, dinv, nullptr);
    swap();
    k_gemm<32, 64, true, true, false>
        <<<(NN + 3) / 4, BLOCK, 0, stream>>>(h, t, w1, b1, nullptr);
    swap();
    // L2 (64->64): transform-first
    k_gemm<64, 64, false, false, true>
        <<<(NN + 3) / 4, BLOCK, 0, stream>>>(h, t, w2, nullptr, dinv);
    swap();
    k_agg<64, 1><<<(NN + 3) / 4, BLOCK, 0, stream>>>(h, t, rowptr, col, dinv, b2);
    swap();
    // L3 (64->32): transform-first (aggregate at F=32)
    k_gemm<64, 32, false, false, true>
        <<<(NN + 7) / 8, BLOCK, 0, stream>>>(h, t, w3, nullptr, dinv);
    swap();
    k_agg<32, 1><<<(NN + 7) / 8, BLOCK, 0, stream>>>(h, t, rowptr, col, dinv, b3);
    swap();
  }

  // out = h @ fc2_w + fc2_b   (N x 32 -> N x 1)
  k_fc2<<<(NN + BLOCK - 1) / BLOCK, BLOCK, 0, stream>>>(h, (float*)d_out, fc2_w, fc2_b);
}

// Round 2
// 1335.633 us; speedup vs baseline: 1.3333x; 1.3333x over previous
//
#include <hip/hip_runtime.h>
#include <hip/hip_fp16.h>

// Problem constants (match reference)
constexpr int NN = 100000;   // nodes
constexpr int EE = 3200000;  // edges
constexpr int BLOCK = 256;
constexpr int SCAN_CHUNK = 1024;
constexpr int SCAN_B = (NN + SCAN_CHUNK - 1) / SCAN_CHUNK;  // 98 blocks

// ---------------- degree / dinv ----------------
__global__ __launch_bounds__(BLOCK) void k_degree(const int* __restrict__ dst,
                                                  int* __restrict__ deg) {
  int e = blockIdx.x * BLOCK + threadIdx.x;
  if (e < EE) atomicAdd(&deg[dst[e]], 1);
}

__global__ __launch_bounds__(BLOCK) void k_dinv(const int* __restrict__ deg,
                                                float* __restrict__ dinv) {
  int i = blockIdx.x * BLOCK + threadIdx.x;
  if (i < NN) dinv[i] = rsqrtf((float)(deg[i] + 1));  // +1 self loop
}

// ---------------- exclusive prefix sum over deg[NN] -> rowptr[NN+1] ----------------
__global__ __launch_bounds__(BLOCK) void k_scan1(const int* __restrict__ v,
                                                 int* __restrict__ bsum) {
  __shared__ int s[BLOCK];
  int base = blockIdx.x * SCAN_CHUNK;
  int t = threadIdx.x;
  int sum = 0;
#pragma unroll
  for (int j = 0; j < 4; ++j) {
    int i = base + t * 4 + j;
    if (i < NN) sum += v[i];
  }
  s[t] = sum;
  __syncthreads();
  for (int off = 128; off > 0; off >>= 1) {
    if (t < off) s[t] += s[t + off];
    __syncthreads();
  }
  if (t == 0) bsum[blockIdx.x] = s[0];
}

__global__ __launch_bounds__(BLOCK) void k_scan2(int* __restrict__ bsum) {
  __shared__ int s[BLOCK];
  int t = threadIdx.x;
  int v = (t < SCAN_B) ? bsum[t] : 0;
  s[t] = v;
  __syncthreads();
  for (int off = 1; off < BLOCK; off <<= 1) {
    int x = (t >= off) ? s[t - off] : 0;
    __syncthreads();
    s[t] += x;
    __syncthreads();
  }
  if (t < SCAN_B) bsum[t] = s[t] - v;        // exclusive
  if (t == BLOCK - 1) bsum[SCAN_B] = s[t];   // total (== EE)
}

__global__ __launch_bounds__(BLOCK) void k_scan3(const int* __restrict__ v,
                                                 const int* __restrict__ bsum,
                                                 int* __restrict__ rowptr) {
  __shared__ int s[BLOCK];
  int base = blockIdx.x * SCAN_CHUNK;
  int t = threadIdx.x;
  int loc[4];
  int sum = 0;
#pragma unroll
  for (int j = 0; j < 4; ++j) {
    int i = base + t * 4 + j;
    loc[j] = (i < NN) ? v[i] : 0;
    sum += loc[j];
  }
  s[t] = sum;
  __syncthreads();
  int own = sum;
  for (int off = 1; off < BLOCK; off <<= 1) {
    int x = (t >= off) ? s[t - off] : 0;
    __syncthreads();
    s[t] += x;
    __syncthreads();
  }
  int ex = s[t] - own + bsum[blockIdx.x];
#pragma unroll
  for (int j = 0; j < 4; ++j) {
    int i = base + t * 4 + j;
    if (i < NN) {
      rowptr[i] = ex;
      ex += loc[j];
    }
  }
  if (blockIdx.x == 0 && t == 0) rowptr[NN] = bsum[SCAN_B];
}

// ---------------- CSR fill ----------------
__global__ __launch_bounds__(BLOCK) void k_fill(const int* __restrict__ src,
                                                const int* __restrict__ dst,
                                                const int* __restrict__ rowptr,
                                                int* __restrict__ fill,
                                                int* __restrict__ col) {
  int e = blockIdx.x * BLOCK + threadIdx.x;
  if (e >= EE) return;
  int d = dst[e];
  int pos = atomicAdd(&fill[d], 1);
  col[rowptr[d] + pos] = src[e];
}

// ---------------- fc1: t0 = (x @ fc1_w + fc1_b) * dinv  (fp16 out) ----------------
__global__ __launch_bounds__(BLOCK) void k_fc1(const float* __restrict__ x,
                                               __half* __restrict__ t0,
                                               const float* __restrict__ W,
                                               const float* __restrict__ b,
                                               const float* __restrict__ dinv) {
  __shared__ float Ws[3 * 32];
  __shared__ float bs[32];
  int tid = threadIdx.x;
  if (tid < 96) Ws[tid] = W[tid];
  if (tid < 32) bs[tid] = b[tid];
  __syncthreads();
  int node = blockIdx.x * 8 + (tid >> 5);
  int f = tid & 31;
  if (node >= NN) return;
  float x0 = x[node * 3], x1 = x[node * 3 + 1], x2 = x[node * 3 + 2];
  float v = fmaf(x0, Ws[f], fmaf(x1, Ws[32 + f], fmaf(x2, Ws[64 + f], bs[f])));
  t0[node * 32 + f] = __float2half(v * dinv[node]);
}

// ---------------- A: t2 = ( relu( S32(t0) @ W1 + b1 ) @ W2 ) * dinv ----------------
// t0: fp16 [N][32] (pre-scaled by dinv). t2: fp16 [N][64].
__global__ __launch_bounds__(BLOCK) void k_A(const __half2* __restrict__ t0,
                                             __half2* __restrict__ t2,
                                             const int* __restrict__ rowptr,
                                             const int* __restrict__ col,
                                             const float* __restrict__ dinv,
                                             const float* __restrict__ W1,
                                             const float* __restrict__ b1,
                                             const float* __restrict__ W2) {
  __shared__ float W1s[32 * 64];
  __shared__ float W2s[64 * 64];
  __shared__ float b1s[64];
  __shared__ float Hs[32 * 33];   // padded stride 33: bank-conflict-free column reads
  __shared__ float H1[32 * 65];   // padded stride 65
  int tid = threadIdx.x;
  for (int i = tid; i < 32 * 64; i += BLOCK) W1s[i] = W1[i];
  for (int i = tid; i < 64 * 64; i += BLOCK) W2s[i] = W2[i];
  if (tid < 64) b1s[tid] = b1[tid];
  __syncthreads();

  int nTiles = (NN + 31) / 32;
  for (int tile = blockIdx.x; tile < nTiles; tile += gridDim.x) {
    // ---- aggregation: 32 nodes in 2 passes of 16, 16 threads/node (half2 lane c) ----
    int c = tid & 15;
#pragma unroll
    for (int p = 0; p < 2; ++p) {
      int ln = p * 16 + (tid >> 4);
      int node = tile * 32 + ln;
      float2 acc = make_float2(0.f, 0.f);
      if (node < NN) {
        acc = __half22float2(t0[(size_t)node * 16 + c]);  // self loop
        int beg = rowptr[node], end = rowptr[node + 1];
#pragma unroll 4
        for (int e = beg; e < end; ++e) {
          float2 v = __half22float2(t0[(size_t)col[e] * 16 + c]);
          acc.x += v.x;
          acc.y += v.y;
        }
        float dv = dinv[node];
        acc.x *= dv;
        acc.y *= dv;
      }
      Hs[ln * 33 + 2 * c] = acc.x;
      Hs[ln * 33 + 2 * c + 1] = acc.y;
    }
    __syncthreads();
    // ---- stage1: H1 = relu(Hs @ W1 + b1)  (32 nodes x 64) ----
    {
      int n = tid >> 3, c8 = tid & 7;
      float a[8];
#pragma unroll
      for (int j = 0; j < 8; ++j) a[j] = b1s[c8 * 8 + j];
#pragma unroll
      for (int k = 0; k < 32; ++k) {
        float h = Hs[n * 33 + k];
#pragma unroll
        for (int j = 0; j < 8; ++j) a[j] = fmaf(h, W1s[k * 64 + c8 * 8 + j], a[j]);
      }
#pragma unroll
      for (int j = 0; j < 8; ++j) H1[n * 65 + c8 * 8 + j] = fmaxf(a[j], 0.f);
    }
    __syncthreads();
    // ---- stage2: t2 = (H1 @ W2) * dinv ----
    {
      int n = tid >> 3, c8 = tid & 7;
      int node = tile * 32 + n;
      float a[8];
#pragma unroll
      for (int j = 0; j < 8; ++j) a[j] = 0.f;
#pragma unroll
      for (int k = 0; k < 64; ++k) {
        float h = H1[n * 65 + k];
#pragma unroll
        for (int j = 0; j < 8; ++j) a[j] = fmaf(h, W2s[k * 64 + c8 * 8 + j], a[j]);
      }
      if (node < NN) {
        float dv = dinv[node];
        __half2* o = t2 + (size_t)node * 32 + c8 * 4;
#pragma unroll
        for (int j = 0; j < 4; ++j)
          o[j] = __float22half2_rn(make_float2(a[2 * j] * dv, a[2 * j + 1] * dv));
      }
    }
    __syncthreads();
  }
}

// ---------------- C: t3 = ( relu( S64agg(t2)*dinv + b2 ) @ W3 ) * dinv ----------------
// t2: fp16 [N][64] (pre-scaled). t3: fp16 [N][32].
__global__ __launch_bounds__(BLOCK) void k_C(const __half2* __restrict__ t2,
                                             __half2* __restrict__ t3,
                                             const int* __restrict__ rowptr,
                                             const int* __restrict__ col,
                                             const float* __restrict__ dinv,
                                             const float* __restrict__ b2,
                                             const float* __restrict__ W3) {
  __shared__ float W3s[64 * 32];
  __shared__ float b2s[64];
  __shared__ float H2[16 * 65];  // padded
  int tid = threadIdx.x;
  for (int i = tid; i < 64 * 32; i += BLOCK) W3s[i] = W3[i];
  if (tid < 64) b2s[tid] = b2[tid];
  __syncthreads();

  int nTiles = (NN + 15) / 16;
  for (int tile = blockIdx.x; tile < nTiles; tile += gridDim.x) {
    int c = tid & 31;
#pragma unroll
    for (int p = 0; p < 2; ++p) {
      int ln = p * 8 + (tid >> 5);
      int node = tile * 16 + ln;
      float2 acc = make_float2(0.f, 0.f);
      if (node < NN) {
        acc = __half22float2(t2[(size_t)node * 32 + c]);  // self loop
        int beg = rowptr[node], end = rowptr[node + 1];
#pragma unroll 4
        for (int e = beg; e < end; ++e) {
          float2 v = __half22float2(t2[(size_t)col[e] * 32 + c]);
          acc.x += v.x;
          acc.y += v.y;
        }
        float dv = dinv[node];
        acc.x = fmaxf(fmaf(acc.x, dv, b2s[2 * c]), 0.f);
        acc.y = fmaxf(fmaf(acc.y, dv, b2s[2 * c + 1]), 0.f);
      }
      H2[ln * 65 + 2 * c] = acc.x;
      H2[ln * 65 + 2 * c + 1] = acc.y;
    }
    __syncthreads();
    {
      int n = tid >> 4, c16 = tid & 15;
      int node = tile * 16 + n;
      float a0 = 0.f, a1 = 0.f;
#pragma unroll
      for (int k = 0; k < 64; ++k) {
        float h = H2[n * 65 + k];
        a0 = fmaf(h, W3s[k * 32 + 2 * c16], a0);
        a1 = fmaf(h, W3s[k * 32 + 2 * c16 + 1], a1);
      }
      if (node < NN) {
        float dv = dinv[node];
        t3[(size_t)node * 16 + c16] =
            __float22half2_rn(make_float2(a0 * dv, a1 * dv));
      }
    }
    __syncthreads();
  }
}

// ---------------- D: h3 = relu(S32agg(t3)*dinv + b3); non-final: t0' = h3*dinv;
//                  final: out = h3 . fc2_w + fc2_b ----------------
template <bool FINAL>
__global__ __launch_bounds__(BLOCK) void k_D(const __half2* __restrict__ t3,
                                             __half2* __restrict__ t0n,
                                             float* __restrict__ out,
                                             const int* __restrict__ rowptr,
                                             const int* __restrict__ col,
                                             const float* __restrict__ dinv,
                                             const float* __restrict__ b3,
                                             const float* __restrict__ fc2w,
                                             const float* __restrict__ fc2b) {
  int tid = threadIdx.x;
  int node = blockIdx.x * 16 + (tid >> 4);
  int c = tid & 15;
  if (node >= NN) return;
  float2 acc = __half22float2(t3[(size_t)node * 16 + c]);  // self loop
  int beg = rowptr[node], end = rowptr[node + 1];
#pragma unroll 4
  for (int e = beg; e < end; ++e) {
    float2 v = __half22float2(t3[(size_t)col[e] * 16 + c]);
    acc.x += v.x;
    acc.y += v.y;
  }
  float dv = dinv[node];
  float h0 = fmaxf(fmaf(acc.x, dv, b3[2 * c]), 0.f);
  float h1 = fmaxf(fmaf(acc.y, dv, b3[2 * c + 1]), 0.f);
  if (!FINAL) {
    t0n[(size_t)node * 16 + c] = __float22half2_rn(make_float2(h0 * dv, h1 * dv));
  } else {
    float part = fmaf(h0, fc2w[2 * c], h1 * fc2w[2 * c + 1]);
#pragma unroll
    for (int off = 8; off > 0; off >>= 1) part += __shfl_down(part, off, 16);
    if (c == 0) out[node] = part + fc2b[0];
  }
}

extern "C" void kernel_launch(void* const* d_in, const int* in_sizes, int n_in,
                              void* d_out, int out_size, void* d_ws, size_t ws_size,
                              hipStream_t stream) {
  const float* x = (const float*)d_in[0];
  const int* ei = (const int*)d_in[1];
  const int* esrc = ei;
  const int* edst = ei + EE;
  const float* fc1_w = (const float*)d_in[2];
  const float* fc1_b = (const float*)d_in[3];
  const float* w1 = (const float*)d_in[4];
  const float* b1 = (const float*)d_in[5];
  const float* w2 = (const float*)d_in[6];
  const float* b2 = (const float*)d_in[7];
  const float* w3 = (const float*)d_in[8];
  const float* b3 = (const float*)d_in[9];
  const float* fc2_w = (const float*)d_in[10];
  const float* fc2_b = (const float*)d_in[11];

  // workspace carve (256B aligned)
  char* p = (char*)d_ws;
  auto carve = [&](size_t bytes) {
    void* r = (void*)p;
    p += (bytes + 255) & ~(size_t)255;
    return r;
  };
  float* dinv = (float*)carve(NN * sizeof(float));
  int* deg = (int*)carve(NN * sizeof(int));
  int* rowptr = (int*)carve((NN + 1) * sizeof(int));
  int* fillp = (int*)carve(NN * sizeof(int));
  int* bsum = (int*)carve((SCAN_B + 1) * sizeof(int));
  int* col = (int*)carve(EE * sizeof(int));
  __half* t32a = (__half*)carve((size_t)NN * 32 * sizeof(__half));
  __half* t64 = (__half*)carve((size_t)NN * 64 * sizeof(__half));
  __half* t32b = (__half*)carve((size_t)NN * 32 * sizeof(__half));

  hipMemsetAsync(deg, 0, NN * sizeof(int), stream);
  hipMemsetAsync(fillp, 0, NN * sizeof(int), stream);

  k_degree<<<EE / BLOCK, BLOCK, 0, stream>>>(edst, deg);
  k_dinv<<<(NN + BLOCK - 1) / BLOCK, BLOCK, 0, stream>>>(deg, dinv);
  k_scan1<<<SCAN_B, BLOCK, 0, stream>>>(deg, bsum);
  k_scan2<<<1, BLOCK, 0, stream>>>(bsum);
  k_scan3<<<SCAN_B, BLOCK, 0, stream>>>(deg, bsum, rowptr);
  k_fill<<<EE / BLOCK, BLOCK, 0, stream>>>(esrc, edst, rowptr, fillp, col);

  // t0 = (x @ fc1_w + fc1_b) * dinv
  k_fc1<<<(NN + 7) / 8, BLOCK, 0, stream>>>(x, t32a, fc1_w, fc1_b, dinv);

  for (int it = 0; it < 4; ++it) {
    k_A<<<1024, BLOCK, 0, stream>>>((const __half2*)t32a, (__half2*)t64,
                                    rowptr, col, dinv, w1, b1, w2);
    k_C<<<2048, BLOCK, 0, stream>>>((const __half2*)t64, (__half2*)t32b,
                                    rowptr, col, dinv, b2, w3);
    if (it < 3) {
      k_D<false><<<(NN + 15) / 16, BLOCK, 0, stream>>>(
          (const __half2*)t32b, (__half2*)t32a, nullptr, rowptr, col, dinv, b3,
          nullptr, nullptr);
    } else {
      k_D<true><<<(NN + 15) / 16, BLOCK, 0, stream>>>(
          (const __half2*)t32b, nullptr, (float*)d_out, rowptr, col, dinv, b3,
          fc2_w, fc2_b);
    }
  }
}

// Round 3
// 1073.046 us; speedup vs baseline: 1.6596x; 1.2447x over previous
//
#include <hip/hip_runtime.h>
#include <hip/hip_fp16.h>

// Problem constants (match reference)
constexpr int NN = 100000;   // nodes
constexpr int EE = 3200000;  // edges
constexpr int BLOCK = 256;
constexpr int SCAN_CHUNK = 1024;
constexpr int SCAN_B = (NN + SCAN_CHUNK - 1) / SCAN_CHUNK;  // 98 blocks

// ---------------- degree (4 edges/thread via int4) ----------------
__global__ __launch_bounds__(BLOCK) void k_degree(const int* __restrict__ dst,
                                                  int* __restrict__ deg) {
  int i = blockIdx.x * BLOCK + threadIdx.x;
  if (i * 4 < EE) {
    int4 d = ((const int4*)dst)[i];
    atomicAdd(&deg[d.x], 1);
    atomicAdd(&deg[d.y], 1);
    atomicAdd(&deg[d.z], 1);
    atomicAdd(&deg[d.w], 1);
  }
}

// ---------------- scan1 (+dinv fused) ----------------
__global__ __launch_bounds__(BLOCK) void k_scan1(const int* __restrict__ v,
                                                 int* __restrict__ bsum,
                                                 float* __restrict__ dinv) {
  __shared__ int s[BLOCK];
  int base = blockIdx.x * SCAN_CHUNK;
  int t = threadIdx.x;
  int sum = 0;
#pragma unroll
  for (int j = 0; j < 4; ++j) {
    int i = base + t * 4 + j;
    if (i < NN) {
      int d = v[i];
      sum += d;
      dinv[i] = rsqrtf((float)(d + 1));  // +1 self loop
    }
  }
  s[t] = sum;
  __syncthreads();
  for (int off = 128; off > 0; off >>= 1) {
    if (t < off) s[t] += s[t + off];
    __syncthreads();
  }
  if (t == 0) bsum[blockIdx.x] = s[0];
}

__global__ __launch_bounds__(BLOCK) void k_scan2(int* __restrict__ bsum) {
  __shared__ int s[BLOCK];
  int t = threadIdx.x;
  int v = (t < SCAN_B) ? bsum[t] : 0;
  s[t] = v;
  __syncthreads();
  for (int off = 1; off < BLOCK; off <<= 1) {
    int x = (t >= off) ? s[t - off] : 0;
    __syncthreads();
    s[t] += x;
    __syncthreads();
  }
  if (t < SCAN_B) bsum[t] = s[t] - v;        // exclusive
  if (t == BLOCK - 1) bsum[SCAN_B] = s[t];   // total (== EE)
}

__global__ __launch_bounds__(BLOCK) void k_scan3(const int* __restrict__ v,
                                                 const int* __restrict__ bsum,
                                                 int* __restrict__ rowptr) {
  __shared__ int s[BLOCK];
  int base = blockIdx.x * SCAN_CHUNK;
  int t = threadIdx.x;
  int loc[4];
  int sum = 0;
#pragma unroll
  for (int j = 0; j < 4; ++j) {
    int i = base + t * 4 + j;
    loc[j] = (i < NN) ? v[i] : 0;
    sum += loc[j];
  }
  s[t] = sum;
  __syncthreads();
  int own = sum;
  for (int off = 1; off < BLOCK; off <<= 1) {
    int x = (t >= off) ? s[t - off] : 0;
    __syncthreads();
    s[t] += x;
    __syncthreads();
  }
  int ex = s[t] - own + bsum[blockIdx.x];
#pragma unroll
  for (int j = 0; j < 4; ++j) {
    int i = base + t * 4 + j;
    if (i < NN) {
      rowptr[i] = ex;
      ex += loc[j];
    }
  }
  if (blockIdx.x == 0 && t == 0) rowptr[NN] = bsum[SCAN_B];
}

// ---------------- CSR fill ----------------
__global__ __launch_bounds__(BLOCK) void k_fill(const int* __restrict__ src,
                                                const int* __restrict__ dst,
                                                const int* __restrict__ rowptr,
                                                int* __restrict__ fill,
                                                int* __restrict__ col) {
  int e = blockIdx.x * BLOCK + threadIdx.x;
  if (e >= EE) return;
  int d = dst[e];
  int pos = atomicAdd(&fill[d], 1);
  col[rowptr[d] + pos] = src[e];
}

// ---------------- fc1: t0 = (x @ fc1_w + fc1_b) * dinv  (fp16 out) ----------------
__global__ __launch_bounds__(BLOCK) void k_fc1(const float* __restrict__ x,
                                               __half* __restrict__ t0,
                                               const float* __restrict__ W,
                                               const float* __restrict__ b,
                                               const float* __restrict__ dinv) {
  __shared__ float Ws[3 * 32];
  __shared__ float bs[32];
  int tid = threadIdx.x;
  if (tid < 96) Ws[tid] = W[tid];
  if (tid < 32) bs[tid] = b[tid];
  __syncthreads();
  int node = blockIdx.x * 8 + (tid >> 5);
  int f = tid & 31;
  if (node >= NN) return;
  float x0 = x[node * 3], x1 = x[node * 3 + 1], x2 = x[node * 3 + 2];
  float v = fmaf(x0, Ws[f], fmaf(x1, Ws[32 + f], fmaf(x2, Ws[64 + f], bs[f])));
  t0[node * 32 + f] = __float2half(v * dinv[node]);
}

// ---------------- A: t1 = relu( (S32(t0))*dinv @ W1 + b1 ) * dinv ----------------
// t0: fp16 [N][32] (pre-scaled). t1: fp16 [N][64]. 32 nodes/block.
__global__ __launch_bounds__(BLOCK) void k_A(const __half2* __restrict__ t0,
                                             __half2* __restrict__ t1,
                                             const int* __restrict__ rowptr,
                                             const int* __restrict__ col,
                                             const float* __restrict__ dinv,
                                             const float* __restrict__ W1,
                                             const float* __restrict__ b1) {
  __shared__ __half2 W1h[32 * 32];  // [k][m] -> cols 2m,2m+1  (4KB)
  __shared__ float b1s[64];
  __shared__ float Hs[32 * 33];     // padded stride 33
  int tid = threadIdx.x;
  for (int i = tid; i < 32 * 32; i += BLOCK) {
    int k = i >> 5, m = i & 31;
    W1h[i] = __floats2half2_rn(W1[k * 64 + 2 * m], W1[k * 64 + 2 * m + 1]);
  }
  if (tid < 64) b1s[tid] = b1[tid];
  __syncthreads();

  int tile = blockIdx.x;
  // ---- aggregation: 32 nodes in 2 passes of 16 node-groups, 16 lanes/node ----
  int c = tid & 15;
#pragma unroll
  for (int p = 0; p < 2; ++p) {
    int ln = p * 16 + (tid >> 4);
    int node = tile * 32 + ln;
    float2 acc = __half22float2(t0[(size_t)node * 16 + c]);  // self loop
    int beg = rowptr[node], end = rowptr[node + 1];
#pragma unroll 8
    for (int e = beg; e < end; ++e) {
      float2 v = __half22float2(t0[(size_t)col[e] * 16 + c]);
      acc.x += v.x;
      acc.y += v.y;
    }
    float dv = dinv[node];
    Hs[ln * 33 + 2 * c] = acc.x * dv;
    Hs[ln * 33 + 2 * c + 1] = acc.y * dv;
  }
  __syncthreads();
  // ---- stage: t1 = relu(Hs @ W1 + b1) * dinv, streamed straight to global ----
  {
    int n = tid >> 3, c8 = tid & 7;  // 8 threads/node, 8 outputs each
    int node = tile * 32 + n;
    float a[8];
#pragma unroll
    for (int j = 0; j < 8; ++j) a[j] = b1s[c8 * 8 + j];
#pragma unroll
    for (int k = 0; k < 32; ++k) {
      float h = Hs[n * 33 + k];
#pragma unroll
      for (int jj = 0; jj < 4; ++jj) {
        float2 w = __half22float2(W1h[k * 32 + c8 * 4 + jj]);
        a[2 * jj] = fmaf(h, w.x, a[2 * jj]);
        a[2 * jj + 1] = fmaf(h, w.y, a[2 * jj + 1]);
      }
    }
    float dv = dinv[node];
    __half2* o = t1 + (size_t)node * 32 + c8 * 4;
#pragma unroll
    for (int jj = 0; jj < 4; ++jj)
      o[jj] = __float22half2_rn(make_float2(fmaxf(a[2 * jj], 0.f) * dv,
                                            fmaxf(a[2 * jj + 1], 0.f) * dv));
  }
}

// ---------------- C: t3 = ( relu((S64(t1))*dinv @ W2 + b2) @ W3 ) * dinv ----------
// t1: fp16 [N][64] (pre-scaled). t3: fp16 [N][32]. 16 nodes/block.
__global__ __launch_bounds__(BLOCK) void k_C(const __half2* __restrict__ t1,
                                             __half2* __restrict__ t3,
                                             const int* __restrict__ rowptr,
                                             const int* __restrict__ col,
                                             const float* __restrict__ dinv,
                                             const float* __restrict__ W2,
                                             const float* __restrict__ b2,
                                             const float* __restrict__ W3) {
  __shared__ __half2 W2h[64 * 32];  // 8KB
  __shared__ __half2 W3h[64 * 16];  // 4KB
  __shared__ float b2s[64];
  __shared__ float H2[16 * 65];     // agg result (u = Â h1)
  __shared__ float G1[16 * 65];     // relu(u @ W2 + b2)
  int tid = threadIdx.x;
  for (int i = tid; i < 64 * 32; i += BLOCK) {
    int k = i >> 5, m = i & 31;
    W2h[i] = __floats2half2_rn(W2[k * 64 + 2 * m], W2[k * 64 + 2 * m + 1]);
  }
  for (int i = tid; i < 64 * 16; i += BLOCK) {
    int k = i >> 4, m = i & 15;
    W3h[i] = __floats2half2_rn(W3[k * 32 + 2 * m], W3[k * 32 + 2 * m + 1]);
  }
  if (tid < 64) b2s[tid] = b2[tid];
  __syncthreads();

  int tile = blockIdx.x;
  // ---- aggregation at F=64: 16 nodes in 2 passes of 8 node-groups, 32 lanes ----
  int c = tid & 31;
#pragma unroll
  for (int p = 0; p < 2; ++p) {
    int ln = p * 8 + (tid >> 5);
    int node = tile * 16 + ln;
    float2 acc = __half22float2(t1[(size_t)node * 32 + c]);  // self loop
    int beg = rowptr[node], end = rowptr[node + 1];
#pragma unroll 8
    for (int e = beg; e < end; ++e) {
      float2 v = __half22float2(t1[(size_t)col[e] * 32 + c]);
      acc.x += v.x;
      acc.y += v.y;
    }
    float dv = dinv[node];
    H2[ln * 65 + 2 * c] = acc.x * dv;
    H2[ln * 65 + 2 * c + 1] = acc.y * dv;
  }
  __syncthreads();
  // ---- stage1: G1 = relu(H2 @ W2 + b2) ----
  {
    int n = tid >> 4, q = tid & 15;  // 16 threads/node, 4 outputs each
    float a[4];
#pragma unroll
    for (int j = 0; j < 4; ++j) a[j] = b2s[q * 4 + j];
#pragma unroll
    for (int k = 0; k < 64; ++k) {
      float h = H2[n * 65 + k];
      float2 w0 = __half22float2(W2h[k * 32 + q * 2]);
      float2 w1 = __half22float2(W2h[k * 32 + q * 2 + 1]);
      a[0] = fmaf(h, w0.x, a[0]);
      a[1] = fmaf(h, w0.y, a[1]);
      a[2] = fmaf(h, w1.x, a[2]);
      a[3] = fmaf(h, w1.y, a[3]);
    }
#pragma unroll
    for (int j = 0; j < 4; ++j) G1[n * 65 + q * 4 + j] = fmaxf(a[j], 0.f);
  }
  __syncthreads();
  // ---- stage2: t3 = (G1 @ W3) * dinv ----
  {
    int n = tid >> 4, c16 = tid & 15;  // 16 threads/node, 2 outputs each
    int node = tile * 16 + n;
    float a0 = 0.f, a1 = 0.f;
#pragma unroll
    for (int k = 0; k < 64; ++k) {
      float h = G1[n * 65 + k];
      float2 w = __half22float2(W3h[k * 16 + c16]);
      a0 = fmaf(h, w.x, a0);
      a1 = fmaf(h, w.y, a1);
    }
    float dv = dinv[node];
    t3[(size_t)node * 16 + c16] = __float22half2_rn(make_float2(a0 * dv, a1 * dv));
  }
}

// ---------------- D: h3 = relu(S32(t3)*dinv + b3); non-final: t0' = h3*dinv;
//                  final: out = h3 . fc2_w + fc2_b ----------------
template <bool FINAL>
__global__ __launch_bounds__(BLOCK) void k_D(const __half2* __restrict__ t3,
                                             __half2* __restrict__ t0n,
                                             float* __restrict__ out,
                                             const int* __restrict__ rowptr,
                                             const int* __restrict__ col,
                                             const float* __restrict__ dinv,
                                             const float* __restrict__ b3,
                                             const float* __restrict__ fc2w,
                                             const float* __restrict__ fc2b) {
  int tid = threadIdx.x;
  int node = blockIdx.x * 16 + (tid >> 4);
  int c = tid & 15;
  if (node >= NN) return;
  float2 acc = __half22float2(t3[(size_t)node * 16 + c]);  // self loop
  int beg = rowptr[node], end = rowptr[node + 1];
#pragma unroll 8
  for (int e = beg; e < end; ++e) {
    float2 v = __half22float2(t3[(size_t)col[e] * 16 + c]);
    acc.x += v.x;
    acc.y += v.y;
  }
  float dv = dinv[node];
  float h0 = fmaxf(fmaf(acc.x, dv, b3[2 * c]), 0.f);
  float h1 = fmaxf(fmaf(acc.y, dv, b3[2 * c + 1]), 0.f);
  if (!FINAL) {
    t0n[(size_t)node * 16 + c] = __float22half2_rn(make_float2(h0 * dv, h1 * dv));
  } else {
    float part = fmaf(h0, fc2w[2 * c], h1 * fc2w[2 * c + 1]);
#pragma unroll
    for (int off = 8; off > 0; off >>= 1) part += __shfl_down(part, off, 16);
    if (c == 0) out[node] = part + fc2b[0];
  }
}

extern "C" void kernel_launch(void* const* d_in, const int* in_sizes, int n_in,
                              void* d_out, int out_size, void* d_ws, size_t ws_size,
                              hipStream_t stream) {
  const float* x = (const float*)d_in[0];
  const int* ei = (const int*)d_in[1];
  const int* esrc = ei;
  const int* edst = ei + EE;
  const float* fc1_w = (const float*)d_in[2];
  const float* fc1_b = (const float*)d_in[3];
  const float* w1 = (const float*)d_in[4];
  const float* b1 = (const float*)d_in[5];
  const float* w2 = (const float*)d_in[6];
  const float* b2 = (const float*)d_in[7];
  const float* w3 = (const float*)d_in[8];
  const float* b3 = (const float*)d_in[9];
  const float* fc2_w = (const float*)d_in[10];
  const float* fc2_b = (const float*)d_in[11];

  // workspace carve (256B aligned)
  char* p = (char*)d_ws;
  auto carve = [&](size_t bytes) {
    void* r = (void*)p;
    p += (bytes + 255) & ~(size_t)255;
    return r;
  };
  float* dinv = (float*)carve(NN * sizeof(float));
  int* degfill = (int*)carve(2 * NN * sizeof(int));  // deg | fillp, one memset
  int* deg = degfill;
  int* fillp = degfill + NN;
  int* rowptr = (int*)carve((NN + 1) * sizeof(int));
  int* bsum = (int*)carve((SCAN_B + 1) * sizeof(int));
  int* col = (int*)carve(EE * sizeof(int));
  __half* t32a = (__half*)carve((size_t)NN * 32 * sizeof(__half));
  __half* t64 = (__half*)carve((size_t)NN * 64 * sizeof(__half));
  __half* t32b = (__half*)carve((size_t)NN * 32 * sizeof(__half));

  hipMemsetAsync(degfill, 0, 2 * NN * sizeof(int), stream);

  k_degree<<<EE / (BLOCK * 4), BLOCK, 0, stream>>>(edst, deg);
  k_scan1<<<SCAN_B, BLOCK, 0, stream>>>(deg, bsum, dinv);
  k_scan2<<<1, BLOCK, 0, stream>>>(bsum);
  k_scan3<<<SCAN_B, BLOCK, 0, stream>>>(deg, bsum, rowptr);
  k_fill<<<EE / BLOCK, BLOCK, 0, stream>>>(esrc, edst, rowptr, fillp, col);

  // t0 = (x @ fc1_w + fc1_b) * dinv
  k_fc1<<<NN / 8, BLOCK, 0, stream>>>(x, t32a, fc1_w, fc1_b, dinv);

  for (int it = 0; it < 4; ++it) {
    k_A<<<NN / 32, BLOCK, 0, stream>>>((const __half2*)t32a, (__half2*)t64,
                                       rowptr, col, dinv, w1, b1);
    k_C<<<NN / 16, BLOCK, 0, stream>>>((const __half2*)t64, (__half2*)t32b,
                                       rowptr, col, dinv, w2, b2, w3);
    if (it < 3) {
      k_D<false><<<NN / 16, BLOCK, 0, stream>>>(
          (const __half2*)t32b, (__half2*)t32a, nullptr, rowptr, col, dinv, b3,
          nullptr, nullptr);
    } else {
      k_D<true><<<NN / 16, BLOCK, 0, stream>>>(
          (const __half2*)t32b, nullptr, (float*)d_out, rowptr, col, dinv, b3,
          fc2_w, fc2_b);
    }
  }
}